// Round 18
// baseline (48.493 us; speedup 1.0000x reference)
//
#include <hip/hip_runtime.h>
#include <hip/hip_bf16.h>
#include <math.h>

// out[i,j] = max( (x[i]·W[j]) / (|x_i| |W_j|), 1e-10 ) + b[j]
// B=65536, IN=OUT=256, fp32 in/out.
// Round 18: R14 with K-QUARTER-INTERLEAVED accumulation. The x drain and the
// LDS/MFMA phase were serial per CU (R17 proved outstanding-depth is not the
// constraint: 128KB/CU DMA in flight -> flat). Here acc[16] holds ALL window
// partials; each arriving x quarter (64 k) is converted and immediately
// MFMA'd into every window (32 ds_read + 32 MFMA per quarter) -> the LDS pipe
// runs INSIDE the drain window. Last quarter fuses scale+store per window
// (stores stream through its compute). Ring-of-2 quarter prefetch, ~1600cyc
// lead. Everything else R14: x-first order, waves0-7 W prologue, one barrier.

using bf16x8 = __attribute__((ext_vector_type(8))) short;   // 8 bf16 = 4 VGPRs
using f32x4  = __attribute__((ext_vector_type(4))) float;

#define W_LDS_BYTES 131072                        // 256 rows * 512 B (bf16, swizzled)
#define LDS_BYTES   (W_LDS_BYTES + 1024 + 1024)   // + winv[256] + b[256]
#define EPS 1e-10f

__device__ __forceinline__ short f2bf(float f) {
    __bf16 h = (__bf16)f;                         // RNE; pairs fuse to v_cvt_pk_bf16_f32
    return __builtin_bit_cast(short, h);
}

__device__ __forceinline__ bf16x8 pack8(float4 a, float4 c) {
    bf16x8 v;
    v[0] = f2bf(a.x); v[1] = f2bf(a.y); v[2] = f2bf(a.z); v[3] = f2bf(a.w);
    v[4] = f2bf(c.x); v[5] = f2bf(c.y); v[6] = f2bf(c.z); v[7] = f2bf(c.w);
    return v;
}

__device__ __forceinline__ float sumsq8(float4 a, float4 c, float s) {
    s = fmaf(a.x, a.x, s); s = fmaf(a.y, a.y, s);
    s = fmaf(a.z, a.z, s); s = fmaf(a.w, a.w, s);
    s = fmaf(c.x, c.x, s); s = fmaf(c.y, c.y, s);
    s = fmaf(c.z, c.z, s); s = fmaf(c.w, c.w, s);
    return s;
}

__global__ __launch_bounds__(1024, 4) void ffn_cosnorm_kernel(
    const float* __restrict__ x, const float* __restrict__ W,
    const float* __restrict__ b, float* __restrict__ out)
{
    extern __shared__ char smem[];
    float* winv = (float*)(smem + W_LDS_BYTES);           // [256] 1/|W_j|
    float* blds = (float*)(smem + W_LDS_BYTES + 1024);    // [256] bias

    const int t    = threadIdx.x;
    const int lane = t & 63;
    const int wave = t >> 6;                  // 0..15
    const int r16  = lane & 15;               // x row within M-tile (= D col, in-lane)
    const int kg   = lane >> 4;               // 0..3 : K-slice of 8
    const int rxor = (r16 & 7) << 4;          // W-frag read swizzle
    const size_t rowb = (size_t)blockIdx.x * 256 + (size_t)wave * 16;

    const float* xp = x + (rowb + r16) * 256 + kg * 8;

    // ---- x quarters 0,1 issued FIRST (x-first order = traffic optimum) ----
    // qb[s][0..1] = k0-even {a,c}, qb[s][2..3] = k0-odd {a,c} of quarter in slot s
    float4 qb[2][4];                          // 32 VGPR ring
    #pragma unroll
    for (int s = 0; s < 2; ++s) {
        qb[s][0] = *(const float4*)(xp + (s * 2) * 32);
        qb[s][1] = *(const float4*)(xp + (s * 2) * 32 + 4);
        qb[s][2] = *(const float4*)(xp + (s * 2 + 1) * 32);
        qb[s][3] = *(const float4*)(xp + (s * 2 + 1) * 32 + 4);
    }

    // ---- W prologue: waves 0-7 only, 2 threads/row (low-conflict layout) ----
    if (wave < 8) {
        const int wrow = t >> 1;              // 0..255 (W row = output col j)
        const int half = t & 1;               // which 128-col half
        const float* wr = W + (size_t)wrow * 256 + half * 128;
        const int rx = (wrow & 7) << 4;       // swizzle term
        float ss = 0.f;
        #pragma unroll
        for (int i = 0; i < 16; ++i) {        // 16 groups of 8 floats
            float4 a = *(const float4*)(wr + i * 8);
            float4 c = *(const float4*)(wr + i * 8 + 4);
            ss = sumsq8(a, c, ss);
            const int off = wrow * 512 + ((half * 256 + i * 16) ^ rx);
            *(bf16x8*)(smem + off) = pack8(a, c);   // ds_write_b128
        }
        ss += __shfl_xor(ss, 1);              // combine the two halves
        if (!half) winv[wrow] = 1.0f / sqrtf(ss);
        if (t < 256) blds[t] = b[t];
    }

    f32x4 acc[16];                            // 64 VGPR: ALL window partials
    #pragma unroll
    for (int n = 0; n < 16; ++n) acc[n] = f32x4{0.f, 0.f, 0.f, 0.f};
    float ssx = 0.f;

    __syncthreads();                          // W staged; only barrier in the kernel

    const int jb = kg * 4;
    float* op = out + (rowb + r16) * 256;

    // ---------------- quarters 0..2: convert, refill ring, accumulate ----------------
    #pragma unroll
    for (int q = 0; q < 3; ++q) {
        const int s = q & 1;                  // static after unroll
        float4 a0 = qb[s][0], c0 = qb[s][1], a1 = qb[s][2], c1 = qb[s][3];
        bf16x8 f0 = pack8(a0, c0);
        bf16x8 f1 = pack8(a1, c1);
        ssx = sumsq8(a0, c0, ssx);
        ssx = sumsq8(a1, c1, ssx);
        if (q < 2) {                          // refill slot with quarter q+2
            const float* p = xp + ((q + 2) * 2) * 32;
            qb[s][0] = *(const float4*)(p);
            qb[s][1] = *(const float4*)(p + 4);
            qb[s][2] = *(const float4*)(p + 32);
            qb[s][3] = *(const float4*)(p + 36);
            __builtin_amdgcn_sched_barrier(0);   // keep refill issue early
        }
        const int cs0 = ((q * 2) * 64 + kg * 16) ^ rxor;
        const int cs1 = ((q * 2 + 1) * 64 + kg * 16) ^ rxor;
        #pragma unroll
        for (int n = 0; n < 16; ++n) {
            const int rowa = (n * 16 + r16) * 512;
            bf16x8 w0 = *(const bf16x8*)(smem + rowa + cs0);   // ds_read_b128
            bf16x8 w1 = *(const bf16x8*)(smem + rowa + cs1);
            acc[n] = __builtin_amdgcn_mfma_f32_16x16x32_bf16(w0, f0, acc[n], 0, 0, 0);
            acc[n] = __builtin_amdgcn_mfma_f32_16x16x32_bf16(w1, f1, acc[n], 0, 0, 0);
        }
    }

    // ---------------- quarter 3: convert, finish ssx, fused compute+store ----------------
    {
        float4 a0 = qb[1][0], c0 = qb[1][1], a1 = qb[1][2], c1 = qb[1][3];
        bf16x8 f0 = pack8(a0, c0);
        bf16x8 f1 = pack8(a1, c1);
        ssx = sumsq8(a0, c0, ssx);
        ssx = sumsq8(a1, c1, ssx);
        ssx += __shfl_xor(ssx, 16); ssx += __shfl_xor(ssx, 32);
        const float inv = 1.0f / sqrtf(ssx);  // 1/|x_row(r16)|, in-lane

        const int cs0 = (6 * 64 + kg * 16) ^ rxor;
        const int cs1 = (7 * 64 + kg * 16) ^ rxor;
        #pragma unroll
        for (int n = 0; n < 16; ++n) {
            const int rowa = (n * 16 + r16) * 512;
            bf16x8 w0 = *(const bf16x8*)(smem + rowa + cs0);
            bf16x8 w1 = *(const bf16x8*)(smem + rowa + cs1);
            f32x4 a = __builtin_amdgcn_mfma_f32_16x16x32_bf16(w0, f0, acc[n], 0, 0, 0);
            a = __builtin_amdgcn_mfma_f32_16x16x32_bf16(w1, f1, a, 0, 0, 0);
            float4 wv = *(const float4*)(winv + n * 16 + jb);
            float4 bv = *(const float4*)(blds + n * 16 + jb);
            f32x4 o;
            o[0] = fmaxf(a[0] * (inv * wv.x), EPS) + bv.x;
            o[1] = fmaxf(a[1] * (inv * wv.y), EPS) + bv.y;
            o[2] = fmaxf(a[2] * (inv * wv.z), EPS) + bv.z;
            o[3] = fmaxf(a[3] * (inv * wv.w), EPS) + bv.w;
            *(f32x4*)(op + n * 16 + jb) = o;  // stores stream through last quarter
        }
    }
}

extern "C" void kernel_launch(void* const* d_in, const int* in_sizes, int n_in,
                              void* d_out, int out_size, void* d_ws, size_t ws_size,
                              hipStream_t stream) {
    const float* x = (const float*)d_in[0];
    const float* W = (const float*)d_in[1];
    const float* b = (const float*)d_in[2];
    float* out = (float*)d_out;

    hipFuncSetAttribute((const void*)ffn_cosnorm_kernel,
                        hipFuncAttributeMaxDynamicSharedMemorySize, LDS_BYTES);
    ffn_cosnorm_kernel<<<dim3(256), dim3(1024), LDS_BYTES, stream>>>(x, W, b, out);
}

// Round 19
// 36.987 us; speedup vs baseline: 1.3111x; 1.3111x over previous
//
#include <hip/hip_runtime.h>
#include <hip/hip_bf16.h>
#include <math.h>

// out[i,j] = max( (x[i]·W[j]) / (|x_i| |W_j|), 1e-10 ) + b[j]
// B=65536, IN=OUT=256, fp32 in/out.
// Round 19: R14 with the barrier de-fanged. __syncthreads drains vmcnt(0) ->
// every wave's compute start was synchronized to the SLOWEST x drain. Here:
//   waves 0-7 : pure x burst at t=0 (traffic-optimal order preserved)
//   waves 8-15: W staging FIRST (L2-hot, ds_writes done ~2us), then x burst
//   raw s_barrier + lgkmcnt(0): W visible, x loads stay in flight
//   conversion AFTER the barrier: each wave starts its n-loop when ITS x
//   lands (progressive vmcnt) -> waves skew; early waves' LDS/MFMA overlaps
//   late waves' drain. Load pattern / n-outer loop / stores: R14 verbatim.

using bf16x8 = __attribute__((ext_vector_type(8))) short;   // 8 bf16 = 4 VGPRs
using f32x4  = __attribute__((ext_vector_type(4))) float;

#define W_LDS_BYTES 131072                        // 256 rows * 512 B (bf16, swizzled)
#define LDS_BYTES   (W_LDS_BYTES + 1024 + 1024)   // + winv[256] + b[256]
#define EPS 1e-10f

__device__ __forceinline__ short f2bf(float f) {
    __bf16 h = (__bf16)f;                         // RNE; pairs fuse to v_cvt_pk_bf16_f32
    return __builtin_bit_cast(short, h);
}

__global__ __launch_bounds__(1024, 4) void ffn_cosnorm_kernel(
    const float* __restrict__ x, const float* __restrict__ W,
    const float* __restrict__ b, float* __restrict__ out)
{
    extern __shared__ char smem[];
    float* winv = (float*)(smem + W_LDS_BYTES);           // [256] 1/|W_j|
    float* blds = (float*)(smem + W_LDS_BYTES + 1024);    // [256] bias

    const int t    = threadIdx.x;
    const int lane = t & 63;
    const int wave = t >> 6;                  // 0..15
    const int r16  = lane & 15;               // x row within M-tile (= D col, in-lane)
    const int kg   = lane >> 4;               // 0..3 : K-slice of 8
    const int rxor = (r16 & 7) << 4;          // W-frag read swizzle
    const size_t rowb = (size_t)blockIdx.x * 256 + (size_t)wave * 16;

    const float* xp = x + (rowb + r16) * 256 + kg * 8;

    // ---- waves 8-15: W staging FIRST (their W loads are oldest -> retire from
    //      L2 fast; ds_writes complete early; x issued after, rides the barrier) ----
    if (wave >= 8) {
        const int tp   = t & 511;             // 0..511
        const int wrow = tp >> 1;             // 0..255 (W row = output col j)
        const int half = tp & 1;              // which 128-col half
        const float* wr = W + (size_t)wrow * 256 + half * 128;
        const int rx = (wrow & 7) << 4;       // swizzle term
        float ss = 0.f;
        #pragma unroll
        for (int i = 0; i < 16; ++i) {        // 16 groups of 8 floats
            float4 a = *(const float4*)(wr + i * 8);
            float4 c = *(const float4*)(wr + i * 8 + 4);
            ss = fmaf(a.x, a.x, ss); ss = fmaf(a.y, a.y, ss);
            ss = fmaf(a.z, a.z, ss); ss = fmaf(a.w, a.w, ss);
            ss = fmaf(c.x, c.x, ss); ss = fmaf(c.y, c.y, ss);
            ss = fmaf(c.z, c.z, ss); ss = fmaf(c.w, c.w, ss);
            bf16x8 v;
            v[0] = f2bf(a.x); v[1] = f2bf(a.y); v[2] = f2bf(a.z); v[3] = f2bf(a.w);
            v[4] = f2bf(c.x); v[5] = f2bf(c.y); v[6] = f2bf(c.z); v[7] = f2bf(c.w);
            const int off = wrow * 512 + ((half * 256 + i * 16) ^ rx);
            *(bf16x8*)(smem + off) = v;       // ds_write_b128 (low-conflict R6 layout)
        }
        ss += __shfl_xor(ss, 1);              // combine the two halves
        if (!half) winv[wrow] = 1.0f / sqrtf(ss);
        if (tp < 256) blds[tp] = b[tp];
    }

    // ---- x burst: waves 0-7 issue at t=0 (x-first, traffic-optimal);
    //      waves 8-15 issue right after their staging ----
    float4 fa[8], fb[8];
    #pragma unroll
    for (int s = 0; s < 8; ++s) {
        fa[s] = *(const float4*)(xp + s * 32);
        fb[s] = *(const float4*)(xp + s * 32 + 4);
    }

    // ---- raw barrier: W ds_writes visible; x loads STAY IN FLIGHT ----
    asm volatile("s_waitcnt lgkmcnt(0)" ::: "memory");
    __builtin_amdgcn_s_barrier();
    __builtin_amdgcn_sched_barrier(0);        // nothing hoists above the barrier

    // ---- convert x -> bf16 fragments + fp32 sum-of-squares (per-wave vmcnt skew) ----
    bf16x8 xb[8];                             // 32 VGPR persistent
    float ssx = 0.f;
    #pragma unroll
    for (int s = 0; s < 8; ++s) {
        float4 a = fa[s], c = fb[s];
        bf16x8 v;
        v[0] = f2bf(a.x); v[1] = f2bf(a.y); v[2] = f2bf(a.z); v[3] = f2bf(a.w);
        v[4] = f2bf(c.x); v[5] = f2bf(c.y); v[6] = f2bf(c.z); v[7] = f2bf(c.w);
        xb[s] = v;
        ssx = fmaf(a.x, a.x, ssx); ssx = fmaf(a.y, a.y, ssx);
        ssx = fmaf(a.z, a.z, ssx); ssx = fmaf(a.w, a.w, ssx);
        ssx = fmaf(c.x, c.x, ssx); ssx = fmaf(c.y, c.y, ssx);
        ssx = fmaf(c.z, c.z, ssx); ssx = fmaf(c.w, c.w, ssx);
    }

    // ---- x_len: butterfly over K-groups; in-lane result ----
    ssx += __shfl_xor(ssx, 16); ssx += __shfl_xor(ssx, 32);
    const float inv = 1.0f / sqrtf(ssx);      // 1/|x_row(r16)|

    // ---------------- n-outer loop (R14 verbatim): compute, store, repeat ----
    const int jb = kg * 4;
    float* op = out + (rowb + r16) * 256;

    #pragma unroll
    for (int n = 0; n < 16; ++n) {
        f32x4 acc = f32x4{0.f, 0.f, 0.f, 0.f};
        #pragma unroll
        for (int k0 = 0; k0 < 8; ++k0) {
            const int addr = (n * 16 + r16) * 512 + ((k0 * 64 + kg * 16) ^ rxor);
            bf16x8 wfr = *(const bf16x8*)(smem + addr);   // ds_read_b128
            acc = __builtin_amdgcn_mfma_f32_16x16x32_bf16(wfr, xb[k0], acc, 0, 0, 0);
        }
        float4 wv = *(const float4*)(winv + n * 16 + jb);
        float4 bv = *(const float4*)(blds + n * 16 + jb);
        f32x4 o;
        o[0] = fmaxf(acc[0] * (inv * wv.x), EPS) + bv.x;
        o[1] = fmaxf(acc[1] * (inv * wv.y), EPS) + bv.y;
        o[2] = fmaxf(acc[2] * (inv * wv.z), EPS) + bv.z;
        o[3] = fmaxf(acc[3] * (inv * wv.w), EPS) + bv.w;
        *(f32x4*)(op + n * 16 + jb) = o;      // stores stream through compute
    }
}

extern "C" void kernel_launch(void* const* d_in, const int* in_sizes, int n_in,
                              void* d_out, int out_size, void* d_ws, size_t ws_size,
                              hipStream_t stream) {
    const float* x = (const float*)d_in[0];
    const float* W = (const float*)d_in[1];
    const float* b = (const float*)d_in[2];
    float* out = (float*)d_out;

    hipFuncSetAttribute((const void*)ffn_cosnorm_kernel,
                        hipFuncAttributeMaxDynamicSharedMemorySize, LDS_BYTES);
    ffn_cosnorm_kernel<<<dim3(256), dim3(1024), LDS_BYTES, stream>>>(x, W, b, out);
}